// Round 1
// baseline (466.176 us; speedup 1.0000x reference)
//
#include <hip/hip_runtime.h>

constexpr int kN = 4, kC = 19, kH = 512, kW = 512;
constexpr int kHW = kH * kW;
constexpr int kS = 2048;      // NUM_SUPERPIXEL
constexpr int kSsm = 8192;    // NUM_SMALL
constexpr float kEps = 1e-8f;

// ---- workspace layout (bytes) ----
constexpr size_t OFF_AMAX = 0;                                   // u64[N*S*C] packed (value_bits<<32)|~pix
constexpr size_t SZ_AMAX  = (size_t)kN * kS * kC * 8;
constexpr size_t OFF_SUM  = OFF_AMAX + SZ_AMAX;                  // f32[N*Ssm*C] nll sumpool
constexpr size_t SZ_SUM   = (size_t)kN * kSsm * kC * 4;
constexpr size_t OFF_CNT  = OFF_SUM + SZ_SUM;                    // i32[N*Ssm] pixel counts
constexpr size_t SZ_CNT   = (size_t)kN * kSsm * 4;
constexpr size_t OFF_ACC  = OFF_CNT + SZ_CNT;                    // f32 loss, i32 nv
constexpr size_t WS_TOTAL = OFF_ACC + 8;

// Weak branch: softmax over C, then per-(segment,channel) lexicographic
// argmax via 64-bit atomicMax of (float_bits(value) << 32) | ~pixel.
// Softmax values are strictly positive => IEEE bits are order-isomorphic.
__global__ void weak_argmax_kernel(const float* __restrict__ logits,
                                   const unsigned char* __restrict__ mask,
                                   const int* __restrict__ seg,
                                   unsigned long long* __restrict__ amax) {
    int gid = blockIdx.x * blockDim.x + threadIdx.x;
    if (gid >= kN * kHW) return;
    if (!mask[gid]) return;
    int n = gid / kHW;
    int p = gid - n * kHW;
    int s = seg[gid];

    const float* base = logits + (size_t)n * kC * kHW + p;
    float x[kC];
    float m = -1e30f;
#pragma unroll
    for (int c = 0; c < kC; ++c) {
        x[c] = base[(size_t)c * kHW];
        m = fmaxf(m, x[c]);
    }
    float sum = 0.f;
#pragma unroll
    for (int c = 0; c < kC; ++c) {
        x[c] = expf(x[c] - m);
        sum += x[c];
    }
    float inv = 1.f / sum;

    unsigned long long lowbits = (unsigned int)(~(unsigned int)p);
    unsigned long long* dst = amax + ((size_t)n * kS + s) * kC;
#pragma unroll
    for (int c = 0; c < kC; ++c) {
        float v = x[c] * inv;
        unsigned long long key = ((unsigned long long)__float_as_uint(v) << 32) | lowbits;
        atomicMax(&dst[c], key);
    }
}

// Strong branch: softmax over C, nll = -log(p + eps), accumulate per
// small-superpixel sumpool and per-small-superpixel masked-pixel counts.
__global__ void strong_sumpool_kernel(const float* __restrict__ logits,
                                      const unsigned char* __restrict__ mask,
                                      const int* __restrict__ seg,
                                      float* __restrict__ sumpool,
                                      int* __restrict__ counts) {
    int gid = blockIdx.x * blockDim.x + threadIdx.x;
    if (gid >= kN * kHW) return;
    if (!mask[gid]) return;
    int n = gid / kHW;
    int p = gid - n * kHW;
    int ss = seg[gid];

    const float* base = logits + (size_t)n * kC * kHW + p;
    float x[kC];
    float m = -1e30f;
#pragma unroll
    for (int c = 0; c < kC; ++c) {
        x[c] = base[(size_t)c * kHW];
        m = fmaxf(m, x[c]);
    }
    float sum = 0.f;
#pragma unroll
    for (int c = 0; c < kC; ++c) {
        x[c] = expf(x[c] - m);
        sum += x[c];
    }
    float inv = 1.f / sum;

    float* dst = sumpool + ((size_t)n * kSsm + ss) * kC;
#pragma unroll
    for (int c = 0; c < kC; ++c) {
        float nll = -logf(x[c] * inv + kEps);
        atomicAdd(&dst[c], nll);
    }
    atomicAdd(&counts[n * kSsm + ss], 1);
}

// Combine: one thread per (n, s, c).
__global__ void combine_kernel(const unsigned long long* __restrict__ amax,
                               const float* __restrict__ targets,
                               const int* __restrict__ small_w,
                               const float* __restrict__ sumpool,
                               const int* __restrict__ counts,
                               float* __restrict__ loss,
                               int* __restrict__ nv) {
    int gid = blockIdx.x * blockDim.x + threadIdx.x;
    float lv = 0.f;
    int nvv = 0;
    if (gid < kN * kS * kC) {
        int n = gid / (kS * kC);
        int rem = gid - n * (kS * kC);
        int s = rem / kC;
        int c = rem - s * kC;
        unsigned long long packed = amax[gid];
        if (packed != 0ULL) {  // segment has at least one masked pixel
            float trg = targets[((size_t)n * kS + s) * (kC + 1) + c];
            if (trg > 0.f) {
                unsigned int pix = ~(unsigned int)(packed & 0xFFFFFFFFULL);
                int sel = small_w[(size_t)n * kHW + pix];
                lv = sumpool[((size_t)n * kSsm + sel) * kC + c];
                nvv = counts[n * kSsm + sel];
            }
        }
    }
    // wave-64 reduction, then one atomic per wave
#pragma unroll
    for (int off = 32; off > 0; off >>= 1) {
        lv += __shfl_down(lv, off);
        nvv += __shfl_down(nvv, off);
    }
    if ((threadIdx.x & 63) == 0 && (lv != 0.f || nvv != 0)) {
        atomicAdd(loss, lv);
        atomicAdd(nv, nvv);
    }
}

__global__ void finalize_kernel(const float* __restrict__ loss,
                                const int* __restrict__ nv,
                                float* __restrict__ out) {
    out[0] = loss[0] / (float)(1 + nv[0]);
}

extern "C" void kernel_launch(void* const* d_in, const int* in_sizes, int n_in,
                              void* d_out, int out_size, void* d_ws, size_t ws_size,
                              hipStream_t stream) {
    const float* inputs            = (const float*)d_in[0];
    const float* inputs_weak       = (const float*)d_in[1];
    const float* targets           = (const float*)d_in[2];
    const unsigned char* spmasks      = (const unsigned char*)d_in[3];  // numpy bool = 1 byte
    const unsigned char* spmasks_weak = (const unsigned char*)d_in[4];
    // d_in[5] superpixels: unused by the reference
    const int* superpixels_weak    = (const int*)d_in[6];
    const int* superpixel_smalls   = (const int*)d_in[7];
    const int* spx_smalls_weak     = (const int*)d_in[8];
    float* out = (float*)d_out;

    unsigned long long* amax = (unsigned long long*)((char*)d_ws + OFF_AMAX);
    float* sumpool           = (float*)((char*)d_ws + OFF_SUM);
    int* counts              = (int*)((char*)d_ws + OFF_CNT);
    float* loss              = (float*)((char*)d_ws + OFF_ACC);
    int* nv                  = (int*)((char*)d_ws + OFF_ACC + 4);

    hipMemsetAsync(d_ws, 0, WS_TOTAL, stream);

    int pixTotal = kN * kHW;
    int blocks = (pixTotal + 255) / 256;
    weak_argmax_kernel<<<blocks, 256, 0, stream>>>(inputs_weak, spmasks_weak,
                                                   superpixels_weak, amax);
    strong_sumpool_kernel<<<blocks, 256, 0, stream>>>(inputs, spmasks,
                                                      superpixel_smalls, sumpool, counts);
    int nscTotal = kN * kS * kC;
    combine_kernel<<<(nscTotal + 255) / 256, 256, 0, stream>>>(amax, targets,
                                                               spx_smalls_weak, sumpool,
                                                               counts, loss, nv);
    finalize_kernel<<<1, 1, 0, stream>>>(loss, nv, out);
}

// Round 2
// 125.294 us; speedup vs baseline: 3.7207x; 3.7207x over previous
//
#include <hip/hip_runtime.h>

constexpr int kN = 4, kC = 19, kH = 512, kW = 512;
constexpr int kHW = kH * kW;
constexpr int kS = 2048;      // NUM_SUPERPIXEL
constexpr int kSsm = 8192;    // NUM_SMALL
constexpr float kEps = 1e-8f;

// ---- workspace layout (bytes) ----
constexpr size_t OFF_AMAX = 0;                                   // u64[N*S*C] (value_bits<<32)|~pix
constexpr size_t SZ_AMAX  = (size_t)kN * kS * kC * 8;
constexpr size_t OFF_SUM  = OFF_AMAX + SZ_AMAX;                  // f32[N*Ssm*C] nll sumpool
constexpr size_t SZ_SUM   = (size_t)kN * kSsm * kC * 4;
constexpr size_t OFF_CNT  = OFF_SUM + SZ_SUM;                    // i32[N*Ssm]
constexpr size_t SZ_CNT   = (size_t)kN * kSsm * 4;
constexpr size_t OFF_TM   = OFF_CNT + SZ_CNT;                    // u32[N*S] target channel bitmask
constexpr size_t SZ_TM    = (size_t)kN * kS * 4;
constexpr size_t OFF_NM   = OFF_TM + SZ_TM;                      // u32[N*Ssm] needed (small,ch) bitmask
constexpr size_t SZ_NM    = (size_t)kN * kSsm * 4;
constexpr size_t OFF_ACC  = OFF_NM + SZ_NM;                      // f32 loss, i32 nv
constexpr size_t WS_TOTAL = OFF_ACC + 8;

// Build per-(n,s) bitmask of channels with target > 0.
__global__ void tmask_kernel(const float* __restrict__ targets,
                             unsigned* __restrict__ tmask) {
    int gid = blockIdx.x * blockDim.x + threadIdx.x;
    if (gid >= kN * kS) return;
    const float* t = targets + (size_t)gid * (kC + 1);
    unsigned m = 0;
#pragma unroll
    for (int c = 0; c < kC; ++c)
        if (t[c] > 0.f) m |= (1u << c);
    tmask[gid] = m;
}

// Weak branch: softmax over C, per-(segment,channel) lexicographic argmax via
// 64-bit atomicMax of (float_bits(v)<<32)|~pixel — only for channels whose
// target bit is set (others are never read by combine).
__global__ void weak_argmax_kernel(const float* __restrict__ logits,
                                   const unsigned char* __restrict__ mask,
                                   const int* __restrict__ seg,
                                   const unsigned* __restrict__ tmask,
                                   unsigned long long* __restrict__ amax) {
    int gid = blockIdx.x * blockDim.x + threadIdx.x;
    if (gid >= kN * kHW) return;
    if (!mask[gid]) return;
    int n = gid / kHW;
    int p = gid - n * kHW;
    int s = seg[gid];
    unsigned tm = tmask[n * kS + s];
    if (!tm) return;

    const float* base = logits + (size_t)n * kC * kHW + p;
    float x[kC];
    float m = -1e30f;
#pragma unroll
    for (int c = 0; c < kC; ++c) {
        x[c] = base[(size_t)c * kHW];
        m = fmaxf(m, x[c]);
    }
    float sum = 0.f;
#pragma unroll
    for (int c = 0; c < kC; ++c) {
        x[c] = expf(x[c] - m);
        sum += x[c];
    }
    float inv = 1.f / sum;

    unsigned long long lowbits = (unsigned int)(~(unsigned int)p);
    unsigned long long* dst = amax + ((size_t)n * kS + s) * kC;
#pragma unroll
    for (int c = 0; c < kC; ++c) {
        if (tm & (1u << c)) {
            float v = x[c] * inv;
            unsigned long long key =
                ((unsigned long long)__float_as_uint(v) << 32) | lowbits;
            atomicMax(&dst[c], key);
        }
    }
}

// Mark which (small, channel) pairs the combine stage will read.
__global__ void need_mark_kernel(const unsigned long long* __restrict__ amax,
                                 const unsigned* __restrict__ tmask,
                                 const int* __restrict__ small_w,
                                 unsigned* __restrict__ needmask) {
    int gid = blockIdx.x * blockDim.x + threadIdx.x;
    if (gid >= kN * kS * kC) return;
    int n = gid / (kS * kC);
    int rem = gid - n * (kS * kC);
    int s = rem / kC;
    int c = rem - s * kC;
    if (!((tmask[n * kS + s] >> c) & 1u)) return;
    unsigned long long packed = amax[gid];
    if (packed == 0ULL) return;  // empty segment
    unsigned pix = ~(unsigned)(packed & 0xFFFFFFFFULL);
    int sel = small_w[(size_t)n * kHW + pix];
    atomicOr(&needmask[n * kSsm + sel], 1u << c);
}

// Strong branch: only pixels whose small-superpixel is needed; only needed
// channels get the nll atomicAdd.
__global__ void strong_sumpool_kernel(const float* __restrict__ logits,
                                      const unsigned char* __restrict__ mask,
                                      const int* __restrict__ seg,
                                      const unsigned* __restrict__ needmask,
                                      float* __restrict__ sumpool,
                                      int* __restrict__ counts) {
    int gid = blockIdx.x * blockDim.x + threadIdx.x;
    if (gid >= kN * kHW) return;
    if (!mask[gid]) return;
    int n = gid / kHW;
    int p = gid - n * kHW;
    int ss = seg[gid];
    unsigned nm = needmask[n * kSsm + ss];
    if (!nm) return;

    const float* base = logits + (size_t)n * kC * kHW + p;
    float x[kC];
    float m = -1e30f;
#pragma unroll
    for (int c = 0; c < kC; ++c) {
        x[c] = base[(size_t)c * kHW];
        m = fmaxf(m, x[c]);
    }
    float sum = 0.f;
#pragma unroll
    for (int c = 0; c < kC; ++c) {
        x[c] = expf(x[c] - m);
        sum += x[c];
    }
    float inv = 1.f / sum;

    float* dst = sumpool + ((size_t)n * kSsm + ss) * kC;
#pragma unroll
    for (int c = 0; c < kC; ++c) {
        if (nm & (1u << c)) {
            float nll = -logf(x[c] * inv + kEps);
            atomicAdd(&dst[c], nll);
        }
    }
    atomicAdd(&counts[n * kSsm + ss], 1);
}

// Combine: one thread per (n, s, c).
__global__ void combine_kernel(const unsigned long long* __restrict__ amax,
                               const unsigned* __restrict__ tmask,
                               const int* __restrict__ small_w,
                               const float* __restrict__ sumpool,
                               const int* __restrict__ counts,
                               float* __restrict__ loss,
                               int* __restrict__ nv) {
    int gid = blockIdx.x * blockDim.x + threadIdx.x;
    float lv = 0.f;
    int nvv = 0;
    if (gid < kN * kS * kC) {
        int n = gid / (kS * kC);
        int rem = gid - n * (kS * kC);
        int s = rem / kC;
        int c = rem - s * kC;
        if ((tmask[n * kS + s] >> c) & 1u) {
            unsigned long long packed = amax[gid];
            if (packed != 0ULL) {
                unsigned pix = ~(unsigned)(packed & 0xFFFFFFFFULL);
                int sel = small_w[(size_t)n * kHW + pix];
                lv = sumpool[((size_t)n * kSsm + sel) * kC + c];
                nvv = counts[n * kSsm + sel];
            }
        }
    }
#pragma unroll
    for (int off = 32; off > 0; off >>= 1) {
        lv += __shfl_down(lv, off);
        nvv += __shfl_down(nvv, off);
    }
    if ((threadIdx.x & 63) == 0 && (lv != 0.f || nvv != 0)) {
        atomicAdd(loss, lv);
        atomicAdd(nv, nvv);
    }
}

__global__ void finalize_kernel(const float* __restrict__ loss,
                                const int* __restrict__ nv,
                                float* __restrict__ out) {
    out[0] = loss[0] / (float)(1 + nv[0]);
}

extern "C" void kernel_launch(void* const* d_in, const int* in_sizes, int n_in,
                              void* d_out, int out_size, void* d_ws, size_t ws_size,
                              hipStream_t stream) {
    const float* inputs            = (const float*)d_in[0];
    const float* inputs_weak       = (const float*)d_in[1];
    const float* targets           = (const float*)d_in[2];
    const unsigned char* spmasks      = (const unsigned char*)d_in[3];
    const unsigned char* spmasks_weak = (const unsigned char*)d_in[4];
    // d_in[5] superpixels: unused by the reference
    const int* superpixels_weak    = (const int*)d_in[6];
    const int* superpixel_smalls   = (const int*)d_in[7];
    const int* spx_smalls_weak     = (const int*)d_in[8];
    float* out = (float*)d_out;

    unsigned long long* amax = (unsigned long long*)((char*)d_ws + OFF_AMAX);
    float* sumpool           = (float*)((char*)d_ws + OFF_SUM);
    int* counts              = (int*)((char*)d_ws + OFF_CNT);
    unsigned* tmask          = (unsigned*)((char*)d_ws + OFF_TM);
    unsigned* needmask       = (unsigned*)((char*)d_ws + OFF_NM);
    float* loss              = (float*)((char*)d_ws + OFF_ACC);
    int* nv                  = (int*)((char*)d_ws + OFF_ACC + 4);

    hipMemsetAsync(d_ws, 0, WS_TOTAL, stream);

    int pixTotal = kN * kHW;
    int pixBlocks = (pixTotal + 255) / 256;
    int nscTotal = kN * kS * kC;
    int nscBlocks = (nscTotal + 255) / 256;

    tmask_kernel<<<(kN * kS + 255) / 256, 256, 0, stream>>>(targets, tmask);
    weak_argmax_kernel<<<pixBlocks, 256, 0, stream>>>(inputs_weak, spmasks_weak,
                                                      superpixels_weak, tmask, amax);
    need_mark_kernel<<<nscBlocks, 256, 0, stream>>>(amax, tmask, spx_smalls_weak,
                                                    needmask);
    strong_sumpool_kernel<<<pixBlocks, 256, 0, stream>>>(inputs, spmasks,
                                                         superpixel_smalls,
                                                         needmask, sumpool, counts);
    combine_kernel<<<nscBlocks, 256, 0, stream>>>(amax, tmask, spx_smalls_weak,
                                                  sumpool, counts, loss, nv);
    finalize_kernel<<<1, 1, 0, stream>>>(loss, nv, out);
}

// Round 3
// 67.640 us; speedup vs baseline: 6.8920x; 1.8524x over previous
//
#include <hip/hip_runtime.h>

constexpr int kN = 4, kC = 19, kH = 512, kW = 512;
constexpr int kHW = kH * kW;
constexpr int kS = 2048;      // NUM_SUPERPIXEL
constexpr int kSsm = 8192;    // NUM_SMALL
constexpr float kEps = 1e-8f;

constexpr int kNSC = kN * kS * kC;                 // combine domain
constexpr int kCombineBlocks = (kNSC + 255) / 256; // 608

// ---- workspace layout (bytes) ----
constexpr size_t OFF_AMAX = 0;                                   // u64[N*S*C] (value_bits<<32)|~pix
constexpr size_t SZ_AMAX  = (size_t)kN * kS * kC * 8;
constexpr size_t OFF_SUM  = OFF_AMAX + SZ_AMAX;                  // f32[N*Ssm*C] nll sumpool
constexpr size_t SZ_SUM   = (size_t)kN * kSsm * kC * 4;
constexpr size_t OFF_CNT  = OFF_SUM + SZ_SUM;                    // i32[N*Ssm]
constexpr size_t SZ_CNT   = (size_t)kN * kSsm * 4;
constexpr size_t OFF_TM   = OFF_CNT + SZ_CNT;                    // u32[N*S] target channel bitmask
constexpr size_t SZ_TM    = (size_t)kN * kS * 4;
constexpr size_t OFF_NM   = OFF_TM + SZ_TM;                      // u32[N*Ssm] needed (small,ch) bitmask
constexpr size_t SZ_NM    = (size_t)kN * kSsm * 4;
constexpr size_t OFF_PL   = OFF_NM + SZ_NM;                      // f32[combineBlocks] loss partials
constexpr size_t SZ_PL    = (size_t)kCombineBlocks * 4;
constexpr size_t OFF_PN   = OFF_PL + SZ_PL;                      // i32[combineBlocks] nv partials
constexpr size_t SZ_PN    = (size_t)kCombineBlocks * 4;
constexpr size_t WS_TOTAL = OFF_PN + SZ_PN;

// Build per-(n,s) bitmask of channels with target > 0.
__global__ void tmask_kernel(const float* __restrict__ targets,
                             unsigned* __restrict__ tmask) {
    int gid = blockIdx.x * blockDim.x + threadIdx.x;
    if (gid >= kN * kS) return;
    const float* t = targets + (size_t)gid * (kC + 1);
    unsigned m = 0;
#pragma unroll
    for (int c = 0; c < kC; ++c)
        if (t[c] > 0.f) m |= (1u << c);
    tmask[gid] = m;
}

// Weak branch: softmax over C, per-(segment,channel) lexicographic argmax via
// 64-bit atomicMax of (float_bits(v)<<32)|~pixel — only for target channels.
__global__ void weak_argmax_kernel(const float* __restrict__ logits,
                                   const unsigned char* __restrict__ mask,
                                   const int* __restrict__ seg,
                                   const unsigned* __restrict__ tmask,
                                   unsigned long long* __restrict__ amax) {
    int gid = blockIdx.x * blockDim.x + threadIdx.x;
    if (gid >= kN * kHW) return;
    if (!mask[gid]) return;
    int n = gid / kHW;
    int p = gid - n * kHW;
    int s = seg[gid];
    unsigned tm = tmask[n * kS + s];
    if (!tm) return;

    const float* base = logits + (size_t)n * kC * kHW + p;
    float x[kC];
    float m = -1e30f;
#pragma unroll
    for (int c = 0; c < kC; ++c) {
        x[c] = base[(size_t)c * kHW];
        m = fmaxf(m, x[c]);
    }
    float sum = 0.f;
#pragma unroll
    for (int c = 0; c < kC; ++c) {
        x[c] = expf(x[c] - m);
        sum += x[c];
    }
    float inv = 1.f / sum;

    unsigned long long lowbits = (unsigned int)(~(unsigned int)p);
    unsigned long long* dst = amax + ((size_t)n * kS + s) * kC;
#pragma unroll
    for (int c = 0; c < kC; ++c) {
        if (tm & (1u << c)) {
            float v = x[c] * inv;
            unsigned long long key =
                ((unsigned long long)__float_as_uint(v) << 32) | lowbits;
            atomicMax(&dst[c], key);
        }
    }
}

// Mark which (small, channel) pairs the combine stage will read.
__global__ void need_mark_kernel(const unsigned long long* __restrict__ amax,
                                 const unsigned* __restrict__ tmask,
                                 const int* __restrict__ small_w,
                                 unsigned* __restrict__ needmask) {
    int gid = blockIdx.x * blockDim.x + threadIdx.x;
    if (gid >= kNSC) return;
    int n = gid / (kS * kC);
    int rem = gid - n * (kS * kC);
    int s = rem / kC;
    int c = rem - s * kC;
    if (!((tmask[n * kS + s] >> c) & 1u)) return;
    unsigned long long packed = amax[gid];
    if (packed == 0ULL) return;  // empty segment
    unsigned pix = ~(unsigned)(packed & 0xFFFFFFFFULL);
    int sel = small_w[(size_t)n * kHW + pix];
    atomicOr(&needmask[n * kSsm + sel], 1u << c);
}

// Strong branch: only pixels whose small-superpixel is needed; only needed
// channels get the nll atomicAdd.
__global__ void strong_sumpool_kernel(const float* __restrict__ logits,
                                      const unsigned char* __restrict__ mask,
                                      const int* __restrict__ seg,
                                      const unsigned* __restrict__ needmask,
                                      float* __restrict__ sumpool,
                                      int* __restrict__ counts) {
    int gid = blockIdx.x * blockDim.x + threadIdx.x;
    if (gid >= kN * kHW) return;
    if (!mask[gid]) return;
    int n = gid / kHW;
    int p = gid - n * kHW;
    int ss = seg[gid];
    unsigned nm = needmask[n * kSsm + ss];
    if (!nm) return;

    const float* base = logits + (size_t)n * kC * kHW + p;
    float x[kC];
    float m = -1e30f;
#pragma unroll
    for (int c = 0; c < kC; ++c) {
        x[c] = base[(size_t)c * kHW];
        m = fmaxf(m, x[c]);
    }
    float sum = 0.f;
#pragma unroll
    for (int c = 0; c < kC; ++c) {
        x[c] = expf(x[c] - m);
        sum += x[c];
    }
    float inv = 1.f / sum;

    float* dst = sumpool + ((size_t)n * kSsm + ss) * kC;
#pragma unroll
    for (int c = 0; c < kC; ++c) {
        if (nm & (1u << c)) {
            float nll = -logf(x[c] * inv + kEps);
            atomicAdd(&dst[c], nll);
        }
    }
    atomicAdd(&counts[n * kSsm + ss], 1);
}

// Combine: one thread per (n, s, c); per-block partials (NO same-address
// atomics — R1 showed 2432 same-line atomics serialize to 61 µs).
__global__ void combine_kernel(const unsigned long long* __restrict__ amax,
                               const unsigned* __restrict__ tmask,
                               const int* __restrict__ small_w,
                               const float* __restrict__ sumpool,
                               const int* __restrict__ counts,
                               float* __restrict__ ploss,
                               int* __restrict__ pnv) {
    __shared__ float sLoss[4];
    __shared__ int sNv[4];
    int gid = blockIdx.x * blockDim.x + threadIdx.x;
    float lv = 0.f;
    int nvv = 0;
    if (gid < kNSC) {
        int n = gid / (kS * kC);
        int rem = gid - n * (kS * kC);
        int s = rem / kC;
        int c = rem - s * kC;
        if ((tmask[n * kS + s] >> c) & 1u) {
            unsigned long long packed = amax[gid];
            if (packed != 0ULL) {
                unsigned pix = ~(unsigned)(packed & 0xFFFFFFFFULL);
                int sel = small_w[(size_t)n * kHW + pix];
                lv = sumpool[((size_t)n * kSsm + sel) * kC + c];
                nvv = counts[n * kSsm + sel];
            }
        }
    }
#pragma unroll
    for (int off = 32; off > 0; off >>= 1) {
        lv += __shfl_down(lv, off);
        nvv += __shfl_down(nvv, off);
    }
    int wave = threadIdx.x >> 6;
    if ((threadIdx.x & 63) == 0) {
        sLoss[wave] = lv;
        sNv[wave] = nvv;
    }
    __syncthreads();
    if (threadIdx.x == 0) {
        float tl = sLoss[0] + sLoss[1] + sLoss[2] + sLoss[3];
        int tn = sNv[0] + sNv[1] + sNv[2] + sNv[3];
        ploss[blockIdx.x] = tl;
        pnv[blockIdx.x] = tn;
    }
}

// Single-block reduction of the per-block partials + final divide.
__global__ void finalize_kernel(const float* __restrict__ ploss,
                                const int* __restrict__ pnv,
                                float* __restrict__ out) {
    __shared__ float sLoss[4];
    __shared__ int sNv[4];
    float lv = 0.f;
    int nvv = 0;
    for (int i = threadIdx.x; i < kCombineBlocks; i += 256) {
        lv += ploss[i];
        nvv += pnv[i];
    }
#pragma unroll
    for (int off = 32; off > 0; off >>= 1) {
        lv += __shfl_down(lv, off);
        nvv += __shfl_down(nvv, off);
    }
    int wave = threadIdx.x >> 6;
    if ((threadIdx.x & 63) == 0) {
        sLoss[wave] = lv;
        sNv[wave] = nvv;
    }
    __syncthreads();
    if (threadIdx.x == 0) {
        float tl = sLoss[0] + sLoss[1] + sLoss[2] + sLoss[3];
        int tn = sNv[0] + sNv[1] + sNv[2] + sNv[3];
        out[0] = tl / (float)(1 + tn);
    }
}

extern "C" void kernel_launch(void* const* d_in, const int* in_sizes, int n_in,
                              void* d_out, int out_size, void* d_ws, size_t ws_size,
                              hipStream_t stream) {
    const float* inputs            = (const float*)d_in[0];
    const float* inputs_weak       = (const float*)d_in[1];
    const float* targets           = (const float*)d_in[2];
    const unsigned char* spmasks      = (const unsigned char*)d_in[3];
    const unsigned char* spmasks_weak = (const unsigned char*)d_in[4];
    // d_in[5] superpixels: unused by the reference
    const int* superpixels_weak    = (const int*)d_in[6];
    const int* superpixel_smalls   = (const int*)d_in[7];
    const int* spx_smalls_weak     = (const int*)d_in[8];
    float* out = (float*)d_out;

    unsigned long long* amax = (unsigned long long*)((char*)d_ws + OFF_AMAX);
    float* sumpool           = (float*)((char*)d_ws + OFF_SUM);
    int* counts              = (int*)((char*)d_ws + OFF_CNT);
    unsigned* tmask          = (unsigned*)((char*)d_ws + OFF_TM);
    unsigned* needmask       = (unsigned*)((char*)d_ws + OFF_NM);
    float* ploss             = (float*)((char*)d_ws + OFF_PL);
    int* pnv                 = (int*)((char*)d_ws + OFF_PN);

    hipMemsetAsync(d_ws, 0, WS_TOTAL, stream);

    int pixTotal = kN * kHW;
    int pixBlocks = (pixTotal + 255) / 256;

    tmask_kernel<<<(kN * kS + 255) / 256, 256, 0, stream>>>(targets, tmask);
    weak_argmax_kernel<<<pixBlocks, 256, 0, stream>>>(inputs_weak, spmasks_weak,
                                                      superpixels_weak, tmask, amax);
    need_mark_kernel<<<kCombineBlocks, 256, 0, stream>>>(amax, tmask, spx_smalls_weak,
                                                         needmask);
    strong_sumpool_kernel<<<pixBlocks, 256, 0, stream>>>(inputs, spmasks,
                                                         superpixel_smalls,
                                                         needmask, sumpool, counts);
    combine_kernel<<<kCombineBlocks, 256, 0, stream>>>(amax, tmask, spx_smalls_weak,
                                                       sumpool, counts, ploss, pnv);
    finalize_kernel<<<1, 256, 0, stream>>>(ploss, pnv, out);
}

// Round 4
// 67.136 us; speedup vs baseline: 6.9438x; 1.0075x over previous
//
#include <hip/hip_runtime.h>

constexpr int kN = 4, kC = 19, kH = 512, kW = 512;
constexpr int kHW = kH * kW;
constexpr int kS = 2048;      // NUM_SUPERPIXEL
constexpr int kSsm = 8192;    // NUM_SMALL
constexpr float kEps = 1e-8f;

constexpr int kNSC = kN * kS * kC;                 // combine domain
constexpr int kCombineBlocks = (kNSC + 255) / 256; // 608

// ---- workspace layout (bytes) ----
constexpr size_t OFF_AMAX = 0;                                   // u64[N*S*C] (value_bits<<32)|~pix
constexpr size_t SZ_AMAX  = (size_t)kN * kS * kC * 8;
constexpr size_t OFF_SUM  = OFF_AMAX + SZ_AMAX;                  // f32[N*Ssm*C] nll sumpool
constexpr size_t SZ_SUM   = (size_t)kN * kSsm * kC * 4;
constexpr size_t OFF_CNT  = OFF_SUM + SZ_SUM;                    // i32[N*Ssm]
constexpr size_t SZ_CNT   = (size_t)kN * kSsm * 4;
constexpr size_t OFF_TM   = OFF_CNT + SZ_CNT;                    // u32[N*S] target channel bitmask
constexpr size_t SZ_TM    = (size_t)kN * kS * 4;
constexpr size_t OFF_NM   = OFF_TM + SZ_TM;                      // u32[N*Ssm] needed (small,ch) bitmask
constexpr size_t SZ_NM    = (size_t)kN * kSsm * 4;
constexpr size_t OFF_PL   = OFF_NM + SZ_NM;                      // f32[combineBlocks] loss partials
constexpr size_t SZ_PL    = (size_t)kCombineBlocks * 4;
constexpr size_t OFF_PN   = OFF_PL + SZ_PL;                      // i32[combineBlocks] nv partials
constexpr size_t SZ_PN    = (size_t)kCombineBlocks * 4;
constexpr size_t WS_RAW   = OFF_PN + SZ_PN;
constexpr size_t WS_TOTAL = (WS_RAW + 15) & ~(size_t)15;         // 16B multiple

// Custom workspace zero-init: hipMemsetAsync's fillBufferAligned ran at
// 88 GB/s / 46 µs for this 4 MB buffer (R2 profile) — grid-stride 16B
// stores at proper grid size do it in ~2 µs.
__global__ void zero_ws_kernel(ulong2* __restrict__ ws) {
    constexpr size_t total16 = WS_TOTAL / 16;
    size_t stride = (size_t)gridDim.x * blockDim.x;
    for (size_t i = blockIdx.x * blockDim.x + threadIdx.x; i < total16; i += stride)
        ws[i] = ulong2{0ULL, 0ULL};
}

// Build per-(n,s) bitmask of channels with target > 0.
__global__ void tmask_kernel(const float* __restrict__ targets,
                             unsigned* __restrict__ tmask) {
    int gid = blockIdx.x * blockDim.x + threadIdx.x;
    if (gid >= kN * kS) return;
    const float* t = targets + (size_t)gid * (kC + 1);
    unsigned m = 0;
#pragma unroll
    for (int c = 0; c < kC; ++c)
        if (t[c] > 0.f) m |= (1u << c);
    tmask[gid] = m;
}

// Weak branch: softmax over C, per-(segment,channel) lexicographic argmax via
// 64-bit atomicMax of (float_bits(v)<<32)|~pixel — only for target channels.
__global__ void weak_argmax_kernel(const float* __restrict__ logits,
                                   const unsigned char* __restrict__ mask,
                                   const int* __restrict__ seg,
                                   const unsigned* __restrict__ tmask,
                                   unsigned long long* __restrict__ amax) {
    int gid = blockIdx.x * blockDim.x + threadIdx.x;
    if (gid >= kN * kHW) return;
    if (!mask[gid]) return;
    int n = gid / kHW;
    int p = gid - n * kHW;
    int s = seg[gid];
    unsigned tm = tmask[n * kS + s];
    if (!tm) return;

    const float* base = logits + (size_t)n * kC * kHW + p;
    float x[kC];
    float m = -1e30f;
#pragma unroll
    for (int c = 0; c < kC; ++c) {
        x[c] = base[(size_t)c * kHW];
        m = fmaxf(m, x[c]);
    }
    float sum = 0.f;
#pragma unroll
    for (int c = 0; c < kC; ++c) {
        x[c] = expf(x[c] - m);
        sum += x[c];
    }
    float inv = 1.f / sum;

    unsigned long long lowbits = (unsigned int)(~(unsigned int)p);
    unsigned long long* dst = amax + ((size_t)n * kS + s) * kC;
#pragma unroll
    for (int c = 0; c < kC; ++c) {
        if (tm & (1u << c)) {
            float v = x[c] * inv;
            unsigned long long key =
                ((unsigned long long)__float_as_uint(v) << 32) | lowbits;
            atomicMax(&dst[c], key);
        }
    }
}

// Mark which (small, channel) pairs the combine stage will read.
__global__ void need_mark_kernel(const unsigned long long* __restrict__ amax,
                                 const unsigned* __restrict__ tmask,
                                 const int* __restrict__ small_w,
                                 unsigned* __restrict__ needmask) {
    int gid = blockIdx.x * blockDim.x + threadIdx.x;
    if (gid >= kNSC) return;
    int n = gid / (kS * kC);
    int rem = gid - n * (kS * kC);
    int s = rem / kC;
    int c = rem - s * kC;
    if (!((tmask[n * kS + s] >> c) & 1u)) return;
    unsigned long long packed = amax[gid];
    if (packed == 0ULL) return;  // empty segment
    unsigned pix = ~(unsigned)(packed & 0xFFFFFFFFULL);
    int sel = small_w[(size_t)n * kHW + pix];
    atomicOr(&needmask[n * kSsm + sel], 1u << c);
}

// Strong branch: only pixels whose small-superpixel is needed; only needed
// channels get the nll atomicAdd.
__global__ void strong_sumpool_kernel(const float* __restrict__ logits,
                                      const unsigned char* __restrict__ mask,
                                      const int* __restrict__ seg,
                                      const unsigned* __restrict__ needmask,
                                      float* __restrict__ sumpool,
                                      int* __restrict__ counts) {
    int gid = blockIdx.x * blockDim.x + threadIdx.x;
    if (gid >= kN * kHW) return;
    if (!mask[gid]) return;
    int n = gid / kHW;
    int p = gid - n * kHW;
    int ss = seg[gid];
    unsigned nm = needmask[n * kSsm + ss];
    if (!nm) return;

    const float* base = logits + (size_t)n * kC * kHW + p;
    float x[kC];
    float m = -1e30f;
#pragma unroll
    for (int c = 0; c < kC; ++c) {
        x[c] = base[(size_t)c * kHW];
        m = fmaxf(m, x[c]);
    }
    float sum = 0.f;
#pragma unroll
    for (int c = 0; c < kC; ++c) {
        x[c] = expf(x[c] - m);
        sum += x[c];
    }
    float inv = 1.f / sum;

    float* dst = sumpool + ((size_t)n * kSsm + ss) * kC;
#pragma unroll
    for (int c = 0; c < kC; ++c) {
        if (nm & (1u << c)) {
            float nll = -logf(x[c] * inv + kEps);
            atomicAdd(&dst[c], nll);
        }
    }
    atomicAdd(&counts[n * kSsm + ss], 1);
}

// Combine: one thread per (n, s, c); per-block partials (R1: same-address
// scalar atomics serialized to 61 µs — never again).
__global__ void combine_kernel(const unsigned long long* __restrict__ amax,
                               const unsigned* __restrict__ tmask,
                               const int* __restrict__ small_w,
                               const float* __restrict__ sumpool,
                               const int* __restrict__ counts,
                               float* __restrict__ ploss,
                               int* __restrict__ pnv) {
    __shared__ float sLoss[4];
    __shared__ int sNv[4];
    int gid = blockIdx.x * blockDim.x + threadIdx.x;
    float lv = 0.f;
    int nvv = 0;
    if (gid < kNSC) {
        int n = gid / (kS * kC);
        int rem = gid - n * (kS * kC);
        int s = rem / kC;
        int c = rem - s * kC;
        if ((tmask[n * kS + s] >> c) & 1u) {
            unsigned long long packed = amax[gid];
            if (packed != 0ULL) {
                unsigned pix = ~(unsigned)(packed & 0xFFFFFFFFULL);
                int sel = small_w[(size_t)n * kHW + pix];
                lv = sumpool[((size_t)n * kSsm + sel) * kC + c];
                nvv = counts[n * kSsm + sel];
            }
        }
    }
#pragma unroll
    for (int off = 32; off > 0; off >>= 1) {
        lv += __shfl_down(lv, off);
        nvv += __shfl_down(nvv, off);
    }
    int wave = threadIdx.x >> 6;
    if ((threadIdx.x & 63) == 0) {
        sLoss[wave] = lv;
        sNv[wave] = nvv;
    }
    __syncthreads();
    if (threadIdx.x == 0) {
        float tl = sLoss[0] + sLoss[1] + sLoss[2] + sLoss[3];
        int tn = sNv[0] + sNv[1] + sNv[2] + sNv[3];
        ploss[blockIdx.x] = tl;
        pnv[blockIdx.x] = tn;
    }
}

// Single-block reduction of the per-block partials + final divide.
__global__ void finalize_kernel(const float* __restrict__ ploss,
                                const int* __restrict__ pnv,
                                float* __restrict__ out) {
    __shared__ float sLoss[4];
    __shared__ int sNv[4];
    float lv = 0.f;
    int nvv = 0;
    for (int i = threadIdx.x; i < kCombineBlocks; i += 256) {
        lv += ploss[i];
        nvv += pnv[i];
    }
#pragma unroll
    for (int off = 32; off > 0; off >>= 1) {
        lv += __shfl_down(lv, off);
        nvv += __shfl_down(nvv, off);
    }
    int wave = threadIdx.x >> 6;
    if ((threadIdx.x & 63) == 0) {
        sLoss[wave] = lv;
        sNv[wave] = nvv;
    }
    __syncthreads();
    if (threadIdx.x == 0) {
        float tl = sLoss[0] + sLoss[1] + sLoss[2] + sLoss[3];
        int tn = sNv[0] + sNv[1] + sNv[2] + sNv[3];
        out[0] = tl / (float)(1 + tn);
    }
}

extern "C" void kernel_launch(void* const* d_in, const int* in_sizes, int n_in,
                              void* d_out, int out_size, void* d_ws, size_t ws_size,
                              hipStream_t stream) {
    const float* inputs            = (const float*)d_in[0];
    const float* inputs_weak       = (const float*)d_in[1];
    const float* targets           = (const float*)d_in[2];
    const unsigned char* spmasks      = (const unsigned char*)d_in[3];
    const unsigned char* spmasks_weak = (const unsigned char*)d_in[4];
    // d_in[5] superpixels: unused by the reference
    const int* superpixels_weak    = (const int*)d_in[6];
    const int* superpixel_smalls   = (const int*)d_in[7];
    const int* spx_smalls_weak     = (const int*)d_in[8];
    float* out = (float*)d_out;

    unsigned long long* amax = (unsigned long long*)((char*)d_ws + OFF_AMAX);
    float* sumpool           = (float*)((char*)d_ws + OFF_SUM);
    int* counts              = (int*)((char*)d_ws + OFF_CNT);
    unsigned* tmask          = (unsigned*)((char*)d_ws + OFF_TM);
    unsigned* needmask       = (unsigned*)((char*)d_ws + OFF_NM);
    float* ploss             = (float*)((char*)d_ws + OFF_PL);
    int* pnv                 = (int*)((char*)d_ws + OFF_PN);

    zero_ws_kernel<<<512, 256, 0, stream>>>((ulong2*)d_ws);

    int pixTotal = kN * kHW;
    int pixBlocks = (pixTotal + 255) / 256;

    tmask_kernel<<<(kN * kS + 255) / 256, 256, 0, stream>>>(targets, tmask);
    weak_argmax_kernel<<<pixBlocks, 256, 0, stream>>>(inputs_weak, spmasks_weak,
                                                      superpixels_weak, tmask, amax);
    need_mark_kernel<<<kCombineBlocks, 256, 0, stream>>>(amax, tmask, spx_smalls_weak,
                                                         needmask);
    strong_sumpool_kernel<<<pixBlocks, 256, 0, stream>>>(inputs, spmasks,
                                                         superpixel_smalls,
                                                         needmask, sumpool, counts);
    combine_kernel<<<kCombineBlocks, 256, 0, stream>>>(amax, tmask, spx_smalls_weak,
                                                       sumpool, counts, ploss, pnv);
    finalize_kernel<<<1, 256, 0, stream>>>(ploss, pnv, out);
}